// Round 2
// baseline (170.013 us; speedup 1.0000x reference)
//
#include <hip/hip_runtime.h>
#include <hip/hip_bf16.h>
#include <math.h>

// Problem constants (fixed by setup_inputs)
#define B_ 4
#define L_ 8192
#define M_ 4096
#define D_ 1024
#define CHUNK_ 16
#define NC_ 256         // M_/CHUNK_
#define EPS_ 1e-4f

// Round-to-nearest-even f32 -> bf16 -> f32 (values are finite here)
__device__ __forceinline__ float bf16rf(float x) {
  unsigned u = __float_as_uint(x);
  u += 0x7FFFu + ((u >> 16) & 1u);
  u &= 0xFFFF0000u;
  return __uint_as_float(u);
}

// boundary_mask may arrive as bool8 (fmt 0), int32 (fmt 1), or float32 (fmt 2)
__device__ __forceinline__ bool mask_at(const void* mb, int fmt, int i) {
  if (fmt == 0) return ((const unsigned char*)mb)[i] != 0;
  if (fmt == 1) return ((const int*)mb)[i] != 0;
  return ((const float*)mb)[i] != 0.0f;
}

// prep1: one block per batch. Detect mask dtype, prefix-sum boundaries,
// scatter p into sorted position (ppos), record boundary rows (rowstart).
__global__ void k_prep1(const float* __restrict__ bprob,
                        const void* __restrict__ bmask,
                        float* __restrict__ ppos,
                        int* __restrict__ rowstart) {
  const int b = blockIdx.x;
  const int tid = threadIdx.x;
  __shared__ int s_flags[2];
  __shared__ int s_psum[256];

  if (tid < 2) s_flags[tid] = 0;
  __syncthreads();
  {
    const unsigned* mw = (const unsigned*)bmask;
    unsigned f0 = 0, f1 = 0;
    for (int i = tid; i < 8192; i += 256) {
      unsigned v = mw[i];
      f0 |= v & 0xFFu;    // byte0: nonzero for u8 and i32, zero for f32
      f1 |= v & 0xFF00u;  // byte1: nonzero only for u8 (45% density)
    }
    if (f1) s_flags[0] = 1;
    if (f0) s_flags[1] = 1;
  }
  __syncthreads();
  const int fmt = s_flags[0] ? 0 : (s_flags[1] ? 1 : 2);

  const int base_l = tid * (L_ / 256);
  int cnt = 0;
  for (int j = 0; j < L_ / 256; ++j)
    cnt += mask_at(bmask, fmt, b * L_ + base_l + j) ? 1 : 0;
  s_psum[tid] = cnt;
  __syncthreads();
  for (int off = 1; off < 256; off <<= 1) {
    int add = (tid >= off) ? s_psum[tid - off] : 0;
    __syncthreads();
    s_psum[tid] += add;
    __syncthreads();
  }
  const int nb = s_psum[255];
  const int excl = s_psum[tid] - cnt;

  for (int r = tid; r <= M_; r += 256) rowstart[b * (M_ + 1) + r] = L_;
  __syncthreads();

  int run = excl;
  for (int j = 0; j < L_ / 256; ++j) {
    int l = base_l + j;
    bool mb = mask_at(bmask, fmt, b * L_ + l);
    int pos;
    if (mb) { pos = run; ++run; }
    else    { pos = nb + (l - run); }
    if (pos < M_) {
      ppos[b * M_ + pos] = bprob[((size_t)(b * L_ + l)) * 2 + 1];
      if (mb) rowstart[b * (M_ + 1) + pos] = l;
    }
  }
}

// prep2: B*M threads. Per-position scalars packed as float4(a, c, 1/dt, 0),
// per-chunk decay product via 16-lane shfl reduction.
__global__ void k_prep2(const float* __restrict__ ppos,
                        float4* __restrict__ scal,
                        float* __restrict__ Achunk) {
  const int g = blockIdx.x * 256 + threadIdx.x;   // 0 .. B_*M_-1
  float p = ppos[g];
  p = fminf(fmaxf(p, EPS_), 1.0f - EPS_);
  float dtf = bf16rf(logf(1.0f / (1.0f - p)));
  float a = expf(-dtf);
  scal[g] = make_float4(a, dtf * p, 1.0f / dtf, 0.0f);
  // product of a over each 16-consecutive-m chunk (aligned to lane groups)
  float prod = a;
  prod *= __shfl_xor(prod, 1);
  prod *= __shfl_xor(prod, 2);
  prod *= __shfl_xor(prod, 4);
  prod *= __shfl_xor(prod, 8);
  if ((g & (CHUNK_ - 1)) == 0) Achunk[g / CHUNK_] = prod;
}

// Pass A: per-(batch, chunk) local scan; emit chunk-end state (zero carry-in).
__global__ void k_scanA(const float* __restrict__ hidden,
                        const float4* __restrict__ scal,
                        const int* __restrict__ rowstart,
                        float* __restrict__ carry) {
  const int c = blockIdx.x, b = blockIdx.y;
  if (rowstart[b * (M_ + 1) + c * CHUNK_] >= L_) return;  // beyond last boundary
  const int d4 = threadIdx.x * 4;
  const int m0 = c * CHUNK_;
  const float* __restrict__ hp = hidden + ((size_t)(b * M_ + m0)) * D_ + d4;
  const float4* __restrict__ sp = scal + b * M_ + m0;
  float hx = 0.f, hy = 0.f, hz = 0.f, hw = 0.f;
#pragma unroll
  for (int m = 0; m < CHUNK_; ++m) {
    const float4 s = sp[m];                       // a, c, 1/dt
    const float4 x = *(const float4*)(hp + (size_t)m * D_);
    hx = fmaf(s.x, hx, s.y * bf16rf(x.x * s.z));
    hy = fmaf(s.x, hy, s.y * bf16rf(x.y * s.z));
    hz = fmaf(s.x, hz, s.y * bf16rf(x.z * s.z));
    hw = fmaf(s.x, hw, s.y * bf16rf(x.w * s.z));
  }
  *(float4*)(carry + ((size_t)(b * NC_ + c)) * D_ + d4) = make_float4(hx, hy, hz, hw);
}

// Pass B: in-place scan across chunks; carry[b,c,d] -> state at END of chunk c.
__global__ void k_scanB(float* __restrict__ carry,
                        const float* __restrict__ Achunk,
                        const int* __restrict__ rowstart) {
  const int b = blockIdx.y;
  const int d = blockIdx.x * 256 + threadIdx.x;
  float S = 0.0f;
  for (int c = 0; c < NC_; ++c) {
    if (rowstart[b * (M_ + 1) + c * CHUNK_] >= L_) break;
    float A = Achunk[b * NC_ + c];
    size_t idx = ((size_t)(b * NC_ + c)) * D_ + d;
    S = fmaf(A, S, carry[idx]);
    carry[idx] = S;
  }
}

// Pass C: recompute local scan with true carry-in, fuse the token scatter.
__global__ void k_scanC(const float* __restrict__ hidden,
                        const float4* __restrict__ scal,
                        const int* __restrict__ rowstart,
                        const float* __restrict__ carry,
                        float* __restrict__ out) {
  const int c = blockIdx.x, b = blockIdx.y;
  const int* __restrict__ rs = rowstart + b * (M_ + 1) + c * CHUNK_;
  if (rs[0] >= L_) return;
  const int d4 = threadIdx.x * 4;
  const int m0 = c * CHUNK_;
  float hx = 0.f, hy = 0.f, hz = 0.f, hw = 0.f;
  if (c > 0) {
    const float4 ci = *(const float4*)(carry + ((size_t)(b * NC_ + c - 1)) * D_ + d4);
    hx = ci.x; hy = ci.y; hz = ci.z; hw = ci.w;
  }
  const float* __restrict__ hp = hidden + ((size_t)(b * M_ + m0)) * D_ + d4;
  const float4* __restrict__ sp = scal + b * M_ + m0;
#pragma unroll
  for (int m = 0; m < CHUNK_; ++m) {
    const float4 s = sp[m];
    const float4 x = *(const float4*)(hp + (size_t)m * D_);
    hx = fmaf(s.x, hx, s.y * bf16rf(x.x * s.z));
    hy = fmaf(s.x, hy, s.y * bf16rf(x.y * s.z));
    hz = fmaf(s.x, hz, s.y * bf16rf(x.z * s.z));
    hw = fmaf(s.x, hw, s.y * bf16rf(x.w * s.z));
    int r0 = rs[m], r1 = rs[m + 1];
    if (r1 > r0) {
      float4 o = make_float4(bf16rf(hx), bf16rf(hy), bf16rf(hz), bf16rf(hw));
      for (int l = r0; l < r1; ++l)
        *(float4*)(out + ((size_t)(b * L_ + l)) * D_ + d4) = o;
    }
  }
}

extern "C" void kernel_launch(void* const* d_in, const int* in_sizes, int n_in,
                              void* d_out, int out_size, void* d_ws, size_t ws_size,
                              hipStream_t stream) {
  const float* hidden = (const float*)d_in[0];
  const float* bprob  = (const float*)d_in[1];
  const void*  bmask  = d_in[2];
  float* out = (float*)d_out;

  float*  ppos    = (float*)d_ws;                            // B*M
  float4* scal    = (float4*)(ppos + B_ * M_);               // B*M float4
  float*  Achunk  = (float*)(scal + B_ * M_);                // B*NC
  float*  carry   = Achunk + B_ * NC_;                       // B*NC*D
  int*    rowstart = (int*)(carry + (size_t)B_ * NC_ * D_);  // B*(M+1)

  k_prep1<<<dim3(B_), dim3(256), 0, stream>>>(bprob, bmask, ppos, rowstart);
  k_prep2<<<dim3(B_ * M_ / 256), dim3(256), 0, stream>>>(ppos, scal, Achunk);
  k_scanA<<<dim3(NC_, B_), dim3(256), 0, stream>>>(hidden, scal, rowstart, carry);
  k_scanB<<<dim3(D_ / 256, B_), dim3(256), 0, stream>>>(carry, Achunk, rowstart);
  k_scanC<<<dim3(NC_, B_), dim3(256), 0, stream>>>(hidden, scal, rowstart, carry, out);
}

// Round 3
// 92.221 us; speedup vs baseline: 1.8435x; 1.8435x over previous
//
#include <hip/hip_runtime.h>
#include <hip/hip_bf16.h>
#include <math.h>

// Problem constants (fixed by setup_inputs)
#define B_ 4
#define L_ 8192
#define M_ 4096
#define D_ 1024
#define CHUNK_ 16
#define NC_ 256         // M_/CHUNK_
#define EPS_ 1e-4f

// Round-to-nearest-even f32 -> bf16 -> f32 (values are finite here)
__device__ __forceinline__ float bf16rf(float x) {
  unsigned u = __float_as_uint(x);
  u += 0x7FFFu + ((u >> 16) & 1u);
  u &= 0xFFFF0000u;
  return __uint_as_float(u);
}

// boundary_mask may arrive as bool8 (fmt 0), int32 (fmt 1), or float32 (fmt 2)
__device__ __forceinline__ bool mask_at(const void* mb, int fmt, int i) {
  if (fmt == 0) return ((const unsigned char*)mb)[i] != 0;
  if (fmt == 1) return ((const int*)mb)[i] != 0;
  return ((const float*)mb)[i] != 0.0f;
}

// prep: one 1024-thread block per batch. Detect mask dtype, prefix-sum
// boundaries, scatter p into sorted order (LDS), emit packed scalars
// (a, c=dt*p, 1/dt), per-16-chunk decay products, and scatter row ranges.
__global__ void __launch_bounds__(1024)
k_prep(const float* __restrict__ bprob,
       const void* __restrict__ bmask,
       float4* __restrict__ scal,
       float* __restrict__ Achunk,
       int* __restrict__ rowstart) {
  const int b = blockIdx.x;
  const int tid = threadIdx.x;  // 0..1023
  __shared__ int s_flags[2];
  __shared__ int s_psum[1024];
  __shared__ float s_p[M_];

  if (tid < 2) s_flags[tid] = 0;
  __syncthreads();
  {
    const unsigned* mw = (const unsigned*)bmask;
    unsigned f0 = 0, f1 = 0;
    for (int i = tid; i < 8192; i += 1024) {
      unsigned v = mw[i];
      f0 |= v & 0xFFu;    // byte0: nonzero for u8 and i32, zero for f32
      f1 |= v & 0xFF00u;  // byte1: nonzero only for u8 (45% density)
    }
    if (f1) s_flags[0] = 1;
    if (f0) s_flags[1] = 1;
  }
  __syncthreads();
  const int fmt = s_flags[0] ? 0 : (s_flags[1] ? 1 : 2);

  // 8 contiguous tokens per thread
  const int base_l = tid * (L_ / 1024);
  bool mloc[L_ / 1024];
  int cnt = 0;
#pragma unroll
  for (int j = 0; j < L_ / 1024; ++j) {
    mloc[j] = mask_at(bmask, fmt, b * L_ + base_l + j);
    cnt += mloc[j] ? 1 : 0;
  }
  s_psum[tid] = cnt;
  __syncthreads();
  for (int off = 1; off < 1024; off <<= 1) {
    int add = (tid >= off) ? s_psum[tid - off] : 0;
    __syncthreads();
    s_psum[tid] += add;
    __syncthreads();
  }
  const int nb = s_psum[1023];
  const int excl = s_psum[tid] - cnt;

  for (int r = tid; r <= M_; r += 1024) rowstart[b * (M_ + 1) + r] = L_;
  __syncthreads();

  int run = excl;
#pragma unroll
  for (int j = 0; j < L_ / 1024; ++j) {
    int l = base_l + j;
    bool mb = mloc[j];
    int pos = mb ? run : (nb + (l - run));
    run += mb ? 1 : 0;
    if (pos < M_) {
      s_p[pos] = bprob[((size_t)(b * L_ + l)) * 2 + 1];
      if (mb) rowstart[b * (M_ + 1) + pos] = l;
    }
  }
  __syncthreads();

  // Per-position scalars + chunk decay products (16-lane shfl groups align
  // with 16-position chunks since stride 1024 preserves m mod 16 == tid mod 16)
#pragma unroll
  for (int i = 0; i < M_ / 1024; ++i) {
    int m = i * 1024 + tid;
    float p = s_p[m];
    p = fminf(fmaxf(p, EPS_), 1.0f - EPS_);
    float dtf = bf16rf(logf(1.0f / (1.0f - p)));
    float a = expf(-dtf);
    scal[b * M_ + m] = make_float4(a, dtf * p, 1.0f / dtf, 0.0f);
    float prod = a;
    prod *= __shfl_xor(prod, 1);
    prod *= __shfl_xor(prod, 2);
    prod *= __shfl_xor(prod, 4);
    prod *= __shfl_xor(prod, 8);
    if ((m & (CHUNK_ - 1)) == 0) Achunk[(b * M_ + m) / CHUNK_] = prod;
  }
}

// Pass A: per-(batch, chunk) local scan; emit chunk-end state (zero carry-in).
__global__ void k_scanA(const float* __restrict__ hidden,
                        const float4* __restrict__ scal,
                        const int* __restrict__ rowstart,
                        float* __restrict__ carry) {
  const int c = blockIdx.x, b = blockIdx.y;
  if (rowstart[b * (M_ + 1) + c * CHUNK_] >= L_) return;  // beyond last boundary
  const int d4 = threadIdx.x * 4;
  const int m0 = c * CHUNK_;
  const float* __restrict__ hp = hidden + ((size_t)(b * M_ + m0)) * D_ + d4;
  const float4* __restrict__ sp = scal + b * M_ + m0;
  float hx = 0.f, hy = 0.f, hz = 0.f, hw = 0.f;
#pragma unroll
  for (int m = 0; m < CHUNK_; ++m) {
    const float4 s = sp[m];                       // a, c, 1/dt
    const float4 x = *(const float4*)(hp + (size_t)m * D_);
    hx = fmaf(s.x, hx, s.y * bf16rf(x.x * s.z));
    hy = fmaf(s.x, hy, s.y * bf16rf(x.y * s.z));
    hz = fmaf(s.x, hz, s.y * bf16rf(x.z * s.z));
    hw = fmaf(s.x, hw, s.y * bf16rf(x.w * s.z));
  }
  *(float4*)(carry + ((size_t)(b * NC_ + c)) * D_ + d4) = make_float4(hx, hy, hz, hw);
}

// Pass B: in-place scan across chunks. Batched: 32 independent loads in
// flight, register fma chain, 32 stores -> one memory latency per 32 chunks.
__global__ void __launch_bounds__(64)
k_scanB(float* __restrict__ carry, const float* __restrict__ Achunk) {
  const int b = blockIdx.y;
  const int d = blockIdx.x * 64 + threadIdx.x;
  const float* __restrict__ Ab = Achunk + b * NC_;
  float S = 0.0f;
  for (int g = 0; g < NC_ / 32; ++g) {
    float v[32], A[32];
#pragma unroll
    for (int j = 0; j < 32; ++j)
      v[j] = carry[((size_t)(b * NC_ + g * 32 + j)) * D_ + d];
#pragma unroll
    for (int j = 0; j < 32; ++j) A[j] = Ab[g * 32 + j];
#pragma unroll
    for (int j = 0; j < 32; ++j) {
      S = fmaf(A[j], S, v[j]);
      v[j] = S;
    }
#pragma unroll
    for (int j = 0; j < 32; ++j)
      carry[((size_t)(b * NC_ + g * 32 + j)) * D_ + d] = v[j];
  }
}

// Pass C: recompute local scan with true carry-in, fuse the token scatter.
__global__ void k_scanC(const float* __restrict__ hidden,
                        const float4* __restrict__ scal,
                        const int* __restrict__ rowstart,
                        const float* __restrict__ carry,
                        float* __restrict__ out) {
  const int c = blockIdx.x, b = blockIdx.y;
  const int* __restrict__ rs = rowstart + b * (M_ + 1) + c * CHUNK_;
  if (rs[0] >= L_) return;
  const int d4 = threadIdx.x * 4;
  const int m0 = c * CHUNK_;
  float hx = 0.f, hy = 0.f, hz = 0.f, hw = 0.f;
  if (c > 0) {
    const float4 ci = *(const float4*)(carry + ((size_t)(b * NC_ + c - 1)) * D_ + d4);
    hx = ci.x; hy = ci.y; hz = ci.z; hw = ci.w;
  }
  const float* __restrict__ hp = hidden + ((size_t)(b * M_ + m0)) * D_ + d4;
  const float4* __restrict__ sp = scal + b * M_ + m0;
#pragma unroll
  for (int m = 0; m < CHUNK_; ++m) {
    const float4 s = sp[m];
    const float4 x = *(const float4*)(hp + (size_t)m * D_);
    hx = fmaf(s.x, hx, s.y * bf16rf(x.x * s.z));
    hy = fmaf(s.x, hy, s.y * bf16rf(x.y * s.z));
    hz = fmaf(s.x, hz, s.y * bf16rf(x.z * s.z));
    hw = fmaf(s.x, hw, s.y * bf16rf(x.w * s.z));
    int r0 = rs[m], r1 = rs[m + 1];
    if (r1 > r0) {
      float4 o = make_float4(bf16rf(hx), bf16rf(hy), bf16rf(hz), bf16rf(hw));
      for (int l = r0; l < r1; ++l)
        *(float4*)(out + ((size_t)(b * L_ + l)) * D_ + d4) = o;
    }
  }
}

extern "C" void kernel_launch(void* const* d_in, const int* in_sizes, int n_in,
                              void* d_out, int out_size, void* d_ws, size_t ws_size,
                              hipStream_t stream) {
  const float* hidden = (const float*)d_in[0];
  const float* bprob  = (const float*)d_in[1];
  const void*  bmask  = d_in[2];
  float* out = (float*)d_out;

  float4* scal    = (float4*)d_ws;                           // B*M float4
  float*  Achunk  = (float*)(scal + B_ * M_);                // B*NC
  float*  carry   = Achunk + B_ * NC_;                       // B*NC*D
  int*    rowstart = (int*)(carry + (size_t)B_ * NC_ * D_);  // B*(M+1)

  k_prep<<<dim3(B_), dim3(1024), 0, stream>>>(bprob, bmask, scal, Achunk, rowstart);
  k_scanA<<<dim3(NC_, B_), dim3(256), 0, stream>>>(hidden, scal, rowstart, carry);
  k_scanB<<<dim3(D_ / 64, B_), dim3(64), 0, stream>>>(carry, Achunk);
  k_scanC<<<dim3(NC_, B_), dim3(256), 0, stream>>>(hidden, scal, rowstart, carry, out);
}